// Round 9
// baseline (37.633 us; speedup 1.0000x reference)
//
#include <hip/hip_runtime.h>

// Problem constants (fixed by the bench: B=8, L=512, T=4096, D=512).
constexpr int B = 8;
constexpr int L = 512;
constexpr int D = 512;
constexpr int T = 4096;
constexpr int TILE = 128;                 // t-columns handled per block
constexpr int DS   = 8;                   // d-splits per (b,chunk)
constexpr int DROWS = D / DS;             // 64 d-rows per block

constexpr int OUT_REP = B * D * T;        // offset of repeats in d_out
constexpr int OUT_LAT = OUT_REP + B * L;  // offset of latent_lengths

// NOTE R9: this is the R7 kernel, launched TWICE (idempotent) as a slope
// probe to separate fixed replay overhead from kernel execution time:
//   dur(R7)  = c + T_k = 20.45 us
//   dur(R9)  = c + 2*T_k
__global__ __launch_bounds__(256) void encoder_expand_kernel(
    const float* __restrict__ enc,   // (B, D, L)
    const float* __restrict__ dur,   // (B, L)
    float* __restrict__ out)         // [expanded (B,D,T) | repeats (B,L) | latent (B)]
{
    const int b     = blockIdx.y;
    const int chunk = blockIdx.x / DS;      // 0..31
    const int ds    = blockIdx.x % DS;      // 0..7
    const int tid   = threadIdx.x;
    const int lane  = tid & 63;
    const int wave  = tid >> 6;             // 0..3

    __shared__ int cums[L + 1];
    __shared__ int l_of_t[TILE];
    __shared__ int wave_tot[4];

    // ---- repeats + inclusive scan over L=512 (2 elems/thread) ----
    const float* durb = dur + b * L;
    const int l0 = tid * 2;
    int r0 = (int)floorf(durb[l0]     + 0.5f);
    int r1 = (int)floorf(durb[l0 + 1] + 0.5f);
    int pair = r0 + r1;

    int scan = pair;                        // wave-level inclusive scan of pair sums
    #pragma unroll
    for (int off = 1; off < 64; off <<= 1) {
        int n = __shfl_up(scan, off, 64);
        if (lane >= off) scan += n;
    }
    if (lane == 63) wave_tot[wave] = scan;
    __syncthreads();

    int wpre = 0;
    #pragma unroll
    for (int w = 0; w < 4; ++w) wpre += (w < wave) ? wave_tot[w] : 0;
    const int excl = wpre + scan - pair;    // exclusive prefix of this thread's pair

    cums[l0 + 1] = excl + r0;
    cums[l0 + 2] = excl + r0 + r1;
    if (tid == 0) cums[0] = 0;
    __syncthreads();

    const int total = cums[L];

    // ---- side outputs (one block per batch does it) ----
    if (chunk == 0 && ds == 0) {
        out[OUT_REP + b * L + l0]     = (float)r0;
        out[OUT_REP + b * L + l0 + 1] = (float)r1;
        if (tid == 0) out[OUT_LAT + b] = (float)total;
    }

    // ---- geometry shared by both paths ----
    const int t0 = chunk * TILE;
    const int tg = tid & 31;                // t-group within tile
    const int dl = tid >> 5;                // 0..7
    const int tt = tg * 4;
    const int d0 = ds * DROWS;
    float* outb = out + (size_t)b * D * T + (size_t)d0 * T + t0 + tt;

    // ---- ZERO FAST PATH: whole tile past latent_length -> pure store stream ----
    if (t0 >= total) {
        const float4 z = make_float4(0.f, 0.f, 0.f, 0.f);
        #pragma unroll
        for (int d = dl; d < DROWS; d += 8)
            *reinterpret_cast<float4*>(outb + (size_t)d * T) = z;
        return;
    }

    // ---- t -> l mapping for this tile (binary search in LDS cums) ----
    if (tid < TILE) {
        const int t = t0 + tid;
        int lo = 0, hi = L;
        while (lo < hi) {
            const int mid = (lo + hi + 1) >> 1;
            if (cums[mid] <= t) lo = mid; else hi = mid - 1;
        }
        l_of_t[tid] = (lo < L) ? lo : -1;   // lo==L  =>  t >= latent_length => 0
    }
    __syncthreads();

    // ---- expansion: thread owns 4 consecutive t, loops over its d slice ----
    const int la = l_of_t[tt];
    const int lb = l_of_t[tt + 1];
    const int lc = l_of_t[tt + 2];
    const int ld = l_of_t[tt + 3];

    const float* encb = enc + (size_t)b * D * L + (size_t)d0 * L;

    const int lax = (la < 0) ? 0 : la;
    const int lbx = (lb < 0) ? 0 : lb;
    const int lcx = (lc < 0) ? 0 : lc;
    const int ldx = (ld < 0) ? 0 : ld;

    #pragma unroll
    for (int d = dl; d < DROWS; d += 8) {
        const float* row = encb + (size_t)d * L;   // 2 KB row, L1/L2-resident
        float4 v;
        v.x = row[lax];
        v.y = row[lbx];
        v.z = row[lcx];
        v.w = row[ldx];
        if (la < 0) v.x = 0.0f;
        if (lb < 0) v.y = 0.0f;
        if (lc < 0) v.z = 0.0f;
        if (ld < 0) v.w = 0.0f;
        *reinterpret_cast<float4*>(outb + (size_t)d * T) = v;
    }
}

extern "C" void kernel_launch(void* const* d_in, const int* in_sizes, int n_in,
                              void* d_out, int out_size, void* d_ws, size_t ws_size,
                              hipStream_t stream) {
    const float* enc = (const float*)d_in[0];   // (B, D, L) fp32
    const float* dur = (const float*)d_in[1];   // (B, L)    fp32
    float* out = (float*)d_out;
    // Slope probe: identical work twice. Output is identical either way.
    encoder_expand_kernel<<<dim3((T / TILE) * DS, B), dim3(256), 0, stream>>>(enc, dur, out);
    encoder_expand_kernel<<<dim3((T / TILE) * DS, B), dim3(256), 0, stream>>>(enc, dur, out);
}

// Round 10
// 17.675 us; speedup vs baseline: 2.1292x; 2.1292x over previous
//
#include <hip/hip_runtime.h>

// Problem constants (fixed by the bench: B=8, L=512, T=4096, D=512).
constexpr int B = 8;
constexpr int L = 512;
constexpr int D = 512;
constexpr int T = 4096;

constexpr int OUT_REP = B * D * T;        // offset of repeats in d_out
constexpr int OUT_LAT = OUT_REP + B * L;  // offset of latent_lengths

// R10: block = (b, pair of adjacent d-rows). Output span per block is one
// CONTIGUOUS 32 KB region, written as 8 sequential block-wide 4 KB sweeps
// (fill-shaped at the DRAM level). Full t->l LUT built in LDS by scatter;
// the 2 enc rows staged in LDS; gathers are conflict-free LDS reads.
__global__ __launch_bounds__(256) void encoder_expand_kernel(
    const float* __restrict__ enc,   // (B, D, L)
    const float* __restrict__ dur,   // (B, L)
    float* __restrict__ out)         // [expanded (B,D,T) | repeats (B,L) | latent (B)]
{
    const int bid = blockIdx.x;
    const int b   = bid >> 8;               // 0..7
    const int rp  = bid & 255;              // row pair 0..255 (d = 2*rp, 2*rp+1)
    const int tid = threadIdx.x;
    const int lane = tid & 63;
    const int wave = tid >> 6;              // 0..3

    __shared__ unsigned short lut[T];       // 8 KB  t -> l, 0xFFFF = past end
    __shared__ float rows[2 * L];           // 4 KB  staged enc rows
    __shared__ int wave_tot[4];

    // ---- issue global loads first (independent) ----
    const float2 dur2 = *reinterpret_cast<const float2*>(dur + b * L + 2 * tid);
    const float* encp = enc + ((size_t)b * D + 2 * rp) * L;   // 2 rows, contiguous
    const float4 rv = reinterpret_cast<const float4*>(encp)[tid];  // 4 KB coalesced

    // ---- init LUT sentinel (2048 u32) while loads are in flight ----
    #pragma unroll
    for (int i = 0; i < T / 2 / 256; ++i)
        reinterpret_cast<unsigned*>(lut)[i * 256 + tid] = 0xFFFFFFFFu;

    // ---- stage enc rows ----
    reinterpret_cast<float4*>(rows)[tid] = rv;

    // ---- repeats + scan over L=512 (2 elems/thread) ----
    const int r0 = (int)floorf(dur2.x + 0.5f);
    const int r1 = (int)floorf(dur2.y + 0.5f);
    const int pair = r0 + r1;

    int scan = pair;                        // wave-level inclusive scan
    #pragma unroll
    for (int off = 1; off < 64; off <<= 1) {
        int n = __shfl_up(scan, off, 64);
        if (lane >= off) scan += n;
    }
    if (lane == 63) wave_tot[wave] = scan;
    __syncthreads();                        // lut init + rows + wave_tot visible

    int wpre = 0;
    #pragma unroll
    for (int w = 0; w < 4; ++w) wpre += (w < wave) ? wave_tot[w] : 0;
    int k = wpre + scan - pair;             // exclusive prefix = t-start of l0's span
    const int total = wave_tot[0] + wave_tot[1] + wave_tot[2] + wave_tot[3];

    // ---- scatter: each l writes its own span (disjoint ranges, no race) ----
    const int l0 = 2 * tid;
    for (int q = 0; q < r0; ++q, ++k) if (k < T) lut[k] = (unsigned short)l0;
    for (int q = 0; q < r1; ++q, ++k) if (k < T) lut[k] = (unsigned short)(l0 + 1);

    // ---- side outputs (one block per batch) ----
    if (rp == 0) {
        out[OUT_REP + b * L + l0]     = (float)r0;
        out[OUT_REP + b * L + l0 + 1] = (float)r1;
        if (tid == 0) out[OUT_LAT + b] = (float)total;
    }
    __syncthreads();                        // scatter done

    // ---- payload: 8 sequential block-wide 4 KB sweeps over the 32 KB span ----
    float4* out4 = reinterpret_cast<float4*>(out + ((size_t)b * D + 2 * rp) * T);

    #pragma unroll
    for (int s = 0; s < 8; ++s) {
        const int row = s >> 2;             // 0..1
        const int seg = s & 3;              // 0..3 (1024-t segment)
        const int t0  = seg * 1024 + 4 * tid;

        float4 v = make_float4(0.f, 0.f, 0.f, 0.f);
        if (seg * 1024 < total) {           // block-uniform zero-skip
            const uint2 lu = *reinterpret_cast<const uint2*>(&lut[t0]);
            const int la = lu.x & 0xffff, lb = lu.x >> 16;
            const int lc = lu.y & 0xffff, ld = lu.y >> 16;
            const float* rowp = rows + row * L;
            v.x = rowp[la & 511];           // monotone l across lanes: ~2-way banks (free)
            v.y = rowp[lb & 511];
            v.z = rowp[lc & 511];
            v.w = rowp[ld & 511];
            if (la == 0xffff) v.x = 0.0f;
            if (lb == 0xffff) v.y = 0.0f;
            if (lc == 0xffff) v.z = 0.0f;
            if (ld == 0xffff) v.w = 0.0f;
        }
        out4[(row * 4 + seg) * 256 + tid] = v;   // block-wide 4 KB sequential store
    }
}

extern "C" void kernel_launch(void* const* d_in, const int* in_sizes, int n_in,
                              void* d_out, int out_size, void* d_ws, size_t ws_size,
                              hipStream_t stream) {
    const float* enc = (const float*)d_in[0];   // (B, D, L) fp32
    const float* dur = (const float*)d_in[1];   // (B, L)    fp32
    float* out = (float*)d_out;
    encoder_expand_kernel<<<dim3(B * (D / 2)), dim3(256), 0, stream>>>(enc, dur, out);
}